// Round 2
// baseline (123.895 us; speedup 1.0000x reference)
//
#include <hip/hip_runtime.h>
#include <hip/hip_bf16.h>

// B=4, N=512, D=64, H=1. All tensors FLOAT32 on device (per reference dtypes);
// internal math f32.
// Input order: 0 h, 1 x, 2 rij, 3 dij, 4 mask, 5 eW1, 6 eb1, 7 eW2, 8 eb2,
// 9 eW3, 10 eb3, 11 pW1, 12 pb1, 13 pW2, 14 pb2, 15 nW1, 16 nb1, 17 nW2,
// 18 nb2, 19 Wih, 20 bih, 21 Whh, 22 bhh.
// Output: h_new (4*512*64) then x_new (4*512*3), float32, concatenated flat.

#define NB 512
#define DB 64
#define ROWS 2048          // B*N
#define H_ELEMS (ROWS * DB)

__device__ __forceinline__ float silu(float x) { return x / (1.0f + __expf(-x)); }
__device__ __forceinline__ float sigmf(float x) { return 1.0f / (1.0f + __expf(-x)); }

// ---------------- Kernel 1: per-node dots + GRU input-collapse vectors ----
// A[row] = h[row,:] . eW1[0:64,0]   (eW1 is (129,1) row-major -> eW1[k])
// C[row] = h[row,:] . eW1[64:128,0]
// U[k]   = nW2[0,:] . Wih[k,:]            (k in [0,192))
// V[k]   = bih[k] + N * (nb2 . Wih[k,:])
__global__ __launch_bounds__(256) void egnn_pre(
    const float* __restrict__ h, const float* __restrict__ eW1,
    const float* __restrict__ nW2, const float* __restrict__ nb2,
    const float* __restrict__ Wih, const float* __restrict__ bih,
    float* __restrict__ A, float* __restrict__ C,
    float* __restrict__ U, float* __restrict__ V)
{
    int t = blockIdx.x * blockDim.x + threadIdx.x;
    if (t < ROWS) {
        const float* hr = h + (size_t)t * DB;
        float sa = 0.0f, sc = 0.0f;
        #pragma unroll 8
        for (int d = 0; d < DB; ++d) {
            float hv = hr[d];
            sa += hv * eW1[d];
            sc += hv * eW1[DB + d];
        }
        A[t] = sa; C[t] = sc;
    } else if (t < ROWS + 3 * DB) {
        int k = t - ROWS;
        const float* wr = Wih + (size_t)k * DB;
        float su = 0.0f, sv = 0.0f;
        #pragma unroll 8
        for (int d = 0; d < DB; ++d) {
            float w = wr[d];
            su += nW2[d] * w;
            sv += nb2[d] * w;
        }
        U[k] = su;
        V[k] = bih[k] + (float)NB * sv;
    }
}

// ---------------- Kernel 2: pairwise chain + reductions + GRU epilogue ----
__global__ __launch_bounds__(256) void egnn_main(
    const float* __restrict__ h, const float* __restrict__ x,
    const float* __restrict__ rij, const float* __restrict__ dij,
    const float* __restrict__ mask,
    const float* __restrict__ eW1, const float* __restrict__ eb1,
    const float* __restrict__ eW2, const float* __restrict__ eb2,
    const float* __restrict__ eW3, const float* __restrict__ eb3,
    const float* __restrict__ pW1, const float* __restrict__ pb1,
    const float* __restrict__ pW2, const float* __restrict__ pb2,
    const float* __restrict__ nW1, const float* __restrict__ nb1,
    const float* __restrict__ Whh, const float* __restrict__ bhh,
    const float* __restrict__ A, const float* __restrict__ C,
    const float* __restrict__ U, const float* __restrict__ V,
    float* __restrict__ out)
{
    const int row = blockIdx.x;          // b*N + i
    const int b   = row >> 9;            // N = 512
    const int tid = threadIdx.x;

    // scalar MLP params (wave-uniform reads; broadcast from cache)
    const float wd  = eW1[2 * DB];
    const float b1  = eb1[0];
    const float w2  = eW2[0],  b2_ = eb2[0];
    const float w3  = eW3[0],  b3  = eb3[0];
    const float pw1 = pW1[0],  pbi = pb1[0];
    const float pw2 = pW2[0],  pbo = pb2[0];
    const float nw1 = nW1[0],  nbi = nb1[0];

    const float ai = A[row];
    const float mi = mask[row];
    const float* Cb = C + (b << 9);
    const float* maskb = mask + (b << 9);
    const float* dr = dij + (size_t)row * NB;
    const float* rr = rij + (size_t)row * NB * 3;

    float S = 0.0f, x0 = 0.0f, x1 = 0.0f, x2 = 0.0f;

    #pragma unroll 2
    for (int j = tid; j < NB; j += 256) {
        float cj = Cb[j];
        float dv = dr[j];
        float mj = maskb[j];
        // edge MLP (H=1 scalar chain)
        float e1  = ai + cj + wd * dv + b1;
        float m1  = silu(e1);
        float m2  = silu(m1 * w2 + b2_);
        float mij = (m2 * w3 + b3) * (mi * mj);   // masked m_ij == mu
        // phi_x head
        float phi = silu(mij * pw1 + pbi) * pw2 + pbo;
        // msg_to_node head (scalar part; nW2 expansion deferred to epilogue)
        float s   = silu(mij * nw1 + nbi);
        S += s;
        int base = j * 3;
        x0 += rr[base + 0] * phi;
        x1 += rr[base + 1] * phi;
        x2 += rr[base + 2] * phi;
    }

    // ---- block reduction: wave64 shuffle, then cross-wave via LDS ----
    #pragma unroll
    for (int off = 32; off > 0; off >>= 1) {
        S  += __shfl_down(S,  off, 64);
        x0 += __shfl_down(x0, off, 64);
        x1 += __shfl_down(x1, off, 64);
        x2 += __shfl_down(x2, off, 64);
    }
    __shared__ float red[4][4];
    __shared__ float fin[4];
    __shared__ float hrow[DB];
    const int wave = tid >> 6, lane = tid & 63;
    if (lane == 0) { red[wave][0] = S; red[wave][1] = x0; red[wave][2] = x1; red[wave][3] = x2; }
    if (tid < DB) hrow[tid] = h[(size_t)row * DB + tid];
    __syncthreads();
    if (tid < 4) fin[tid] = red[0][tid] + red[1][tid] + red[2][tid] + red[3][tid];
    __syncthreads();

    // ---- GRU epilogue: lanes 0..63 each produce one output channel ----
    if (tid < DB) {
        const float Sf = fin[0];
        const int d = tid;
        const float* Wr = Whh + (size_t)d * DB;
        const float* Wz = Whh + (size_t)(DB + d) * DB;
        const float* Wn = Whh + (size_t)(2 * DB + d) * DB;
        float ghr = bhh[d];
        float ghz = bhh[DB + d];
        float ghn = bhh[2 * DB + d];
        #pragma unroll 8
        for (int k = 0; k < DB; ++k) {
            float hv = hrow[k];
            ghr += hv * Wr[k];
            ghz += hv * Wz[k];
            ghn += hv * Wn[k];
        }
        float gir = Sf * U[d]          + V[d];
        float giz = Sf * U[DB + d]     + V[DB + d];
        float gin = Sf * U[2 * DB + d] + V[2 * DB + d];
        float r = sigmf(gir + ghr);
        float z = sigmf(giz + ghz);
        float n = tanhf(gin + r * ghn);
        float hn = (1.0f - z) * n + z * hrow[d];
        hn *= mi;
        out[(size_t)row * DB + d] = hn;
    } else if (tid < DB + 3) {
        const int ci = tid - DB;
        float xv = x[row * 3 + ci] + fin[1 + ci];
        out[H_ELEMS + row * 3 + ci] = xv;
    }
}

extern "C" void kernel_launch(void* const* d_in, const int* in_sizes, int n_in,
                              void* d_out, int out_size, void* d_ws, size_t ws_size,
                              hipStream_t stream) {
    const float* h    = (const float*)d_in[0];
    const float* x    = (const float*)d_in[1];
    const float* rij  = (const float*)d_in[2];
    const float* dij  = (const float*)d_in[3];
    const float* mask = (const float*)d_in[4];
    const float* eW1  = (const float*)d_in[5];
    const float* eb1  = (const float*)d_in[6];
    const float* eW2  = (const float*)d_in[7];
    const float* eb2  = (const float*)d_in[8];
    const float* eW3  = (const float*)d_in[9];
    const float* eb3  = (const float*)d_in[10];
    const float* pW1  = (const float*)d_in[11];
    const float* pb1  = (const float*)d_in[12];
    const float* pW2  = (const float*)d_in[13];
    const float* pb2  = (const float*)d_in[14];
    const float* nW1  = (const float*)d_in[15];
    const float* nb1  = (const float*)d_in[16];
    const float* nW2  = (const float*)d_in[17];
    const float* nb2  = (const float*)d_in[18];
    const float* Wih  = (const float*)d_in[19];
    const float* bih  = (const float*)d_in[20];
    const float* Whh  = (const float*)d_in[21];
    const float* bhh  = (const float*)d_in[22];

    float* A = (float*)d_ws;            // 2048
    float* C = A + ROWS;                // 2048
    float* U = C + ROWS;                // 192
    float* V = U + 3 * DB;              // 192

    egnn_pre<<<(ROWS + 3 * DB + 255) / 256, 256, 0, stream>>>(
        h, eW1, nW2, nb2, Wih, bih, A, C, U, V);

    egnn_main<<<ROWS, 256, 0, stream>>>(
        h, x, rij, dij, mask,
        eW1, eb1, eW2, eb2, eW3, eb3,
        pW1, pb1, pW2, pb2, nW1, nb1,
        Whh, bhh, A, C, U, V,
        (float*)d_out);
}